// Round 2
// baseline (102.206 us; speedup 1.0000x reference)
//
#include <hip/hip_runtime.h>

// Box_diamond: soft-product gate network.
// out[b,p] = softprod_m(1 - y1[b,p,m]*W2[p,m]),
// y1[b,p,m] = softprod_l(1 - x[b, (p>>2)*32 + l*4 + (p&3)] * W1[p,l-m]),
// W1[p,d] = sigmoid(d*(t2[p]-d)) (15 values), softprod(X) = 1/(1 - ln(prod X)).
// All factors >= 0.5 (W1,W2 <= 0.5, x < 1) so one log per 8-product is safe.
//
// Structure: wave-private LDS staging. Each wave stages one 512-float row
// chunk with 2 coalesced float4 wave-loads, XOR-swizzled into LDS so both
// the b128 writes and the per-l reads are bank-conflict-free. 2-deep
// pipeline (next-row global loads issued before current-row compute).
// Gate tables precomputed once into d_ws by a tiny kernel.

constexpr int IN_DIM = 4096;
constexpr int PDIM   = 512;
constexpr int BDIM   = 4096;
constexpr int PT = 64;   // p per block
constexpr int BT = 16;   // b rows per block (4 per wave)
constexpr float LN2 = 0.69314718055994530942f;

__global__ void box_table_kernel(const float* __restrict__ t0,
                                 const float* __restrict__ t1,
                                 const float* __restrict__ t2,
                                 float* __restrict__ tab)
{
    const int p = blockIdx.x * blockDim.x + threadIdx.x;
    if (p >= PDIM) return;
    const float t0p = t0[p], t1p = t1[p], t2p = t2[p];
#pragma unroll
    for (int d = -7; d <= 7; ++d) {
        const float fd = (float)d;
        tab[(d + 7) * PDIM + p] = 1.0f / (1.0f + __expf(-(fd * (t2p - fd))));
    }
#pragma unroll
    for (int m = 0; m < 8; ++m) {
        const float fm = (float)m;
        const float sa = 1.0f / (1.0f + __expf(-((fm - t0p) * (t1p - fm))));
        const float sb = 1.0f / (1.0f + __expf(-((7.0f - t2p - fm) * fm)));
        tab[(15 + m) * PDIM + p] = sa * sb;
    }
}

__global__ __launch_bounds__(256, 4)
void box_main_kernel(const float* __restrict__ x,
                     const float* __restrict__ tab,
                     float* __restrict__ out)
{
    __shared__ float lds[4][2][512];   // [wave][buf][float] = 16 KB, wave-private

    const int t    = threadIdx.x;
    const int w    = t >> 6;
    const int lane = t & 63;
    const int p0   = blockIdx.x * PT;
    const int b0   = blockIdx.y * BT;
    const int p    = p0 + lane;

    // per-lane gate tables (coalesced: tab layout is [23][PDIM])
    float w1d[15];
#pragma unroll
    for (int i = 0; i < 15; ++i) w1d[i] = tab[i * PDIM + p];
    float w2v[8];
#pragma unroll
    for (int m = 0; m < 8; ++m) w2v[m] = tab[(15 + m) * PDIM + p];

    // staging side: lane holds float4 k: (g = 8k + (lane>>3), l = lane&7, j = 0..3)
    // LDS addr(G,L,J) = L*64 + ((G^L)&15)*4 + J  (XOR swizzle, conflict-free)
    const int ls = lane & 7;
    const int gh = lane >> 3;
    float* const mybuf  = &lds[w][0][0];
    float* const wraddr = mybuf + ls * 64 + ((gh ^ ls) << 2);   // k=0; k=1 at +32

    // compute side: this lane's (g, j)
    const int gr = lane >> 2, jr = lane & 3;

    const int brow = b0 + w * 4;
    const float* const xrow = x + (size_t)brow * IN_DIM + p0 * 8;
    float* const orow = out + (size_t)brow * PDIM + p;

    // prologue: stage row 0 into buf 0
    {
        const float4* s = (const float4*)xrow;
        float4 a0 = s[lane];
        float4 a1 = s[64 + lane];
        *(float4*)(wraddr)      = a0;
        *(float4*)(wraddr + 32) = a1;
    }

#pragma unroll
    for (int r = 0; r < 4; ++r) {
        // issue next row's global loads early (latency hides under compute)
        float4 n0, n1;
        if (r < 3) {
            const float4* s = (const float4*)(xrow + (size_t)(r + 1) * IN_DIM);
            n0 = s[lane];
            n1 = s[64 + lane];
        }

        const float* buf = mybuf + (r & 1) * 512;
        float xv[8];
#pragma unroll
        for (int l = 0; l < 8; ++l)
            xv[l] = buf[l * 64 + ((gr ^ l) << 2) + jr];

        float c[8];
#pragma unroll
        for (int m = 0; m < 8; ++m) {
            float f0 = 1.0f - xv[0] * w1d[7 - m];
            float f1 = 1.0f - xv[1] * w1d[8 - m];
            float f2 = 1.0f - xv[2] * w1d[9 - m];
            float f3 = 1.0f - xv[3] * w1d[10 - m];
            float f4 = 1.0f - xv[4] * w1d[11 - m];
            float f5 = 1.0f - xv[5] * w1d[12 - m];
            float f6 = 1.0f - xv[6] * w1d[13 - m];
            float f7 = 1.0f - xv[7] * w1d[14 - m];
            const float pr = ((f0 * f1) * (f2 * f3)) * ((f4 * f5) * (f6 * f7));
            const float y1 = __builtin_amdgcn_rcpf(1.0f - LN2 * __log2f(pr));
            c[m] = 1.0f - y1 * w2v[m];
        }
        const float pr2 = ((c[0] * c[1]) * (c[2] * c[3])) * ((c[4] * c[5]) * (c[6] * c[7]));
        const float res = __builtin_amdgcn_rcpf(1.0f - LN2 * __log2f(pr2));

        // write next row into the other buffer (vmcnt wait lands here, after compute)
        if (r < 3) {
            float* wa = wraddr + (((r + 1) & 1) ? 512 : 0);
            *(float4*)(wa)      = n0;
            *(float4*)(wa + 32) = n1;
        }

        orow[r * PDIM] = res;
    }
}

extern "C" void kernel_launch(void* const* d_in, const int* in_sizes, int n_in,
                              void* d_out, int out_size, void* d_ws, size_t ws_size,
                              hipStream_t stream)
{
    const float* x  = (const float*)d_in[0];
    const float* t0 = (const float*)d_in[1];
    const float* t1 = (const float*)d_in[2];
    const float* t2 = (const float*)d_in[3];
    float* out = (float*)d_out;
    float* tab = (float*)d_ws;   // 23 * 512 floats

    box_table_kernel<<<2, 256, 0, stream>>>(t0, t1, t2, tab);
    dim3 grid(PDIM / PT, BDIM / BT);   // (8, 256) = 2048 blocks
    box_main_kernel<<<grid, 256, 0, stream>>>(x, tab, out);
}

// Round 3
// 100.067 us; speedup vs baseline: 1.0214x; 1.0214x over previous
//
#include <hip/hip_runtime.h>

// Box_diamond: soft-product gate network.
// out[b,p] = softprod_m(1 - y1[b,p,m]*W2[p,m]),
// y1[b,p,m] = softprod_l(1 - x[b,(p>>2)*32+l*4+(p&3)] * W1[p,l-m]),
// W1[p,d] = sigmoid(d*(t2[p]-d)) (15 vals/p), softprod(X) = 1/(1 - ln(prod X)).
// All layer-1 factors in [0.5,1] (W1<=0.5, x<1) -> one log per 8-product.
// Division trick: c[m] = (den[m]-w2[m])/den[m], den[m] = 1 - ln p1[m] in [1,6.55];
// out = 1/(1 - LN2*(log2(prod num) - log2(prod den))) -> 11 transcendentals/output.
//
// Single fused kernel. Wave-private double-buffered LDS staging of 2-row
// batches (XOR-swizzled, bank-conflict-free both sides), depth-1 prefetch:
// next batch's 4 dwordx4 global loads issue before current batch's ~1000-cycle
// compute, vmcnt wait lands after it. No barriers in the main loop.

constexpr int IN_DIM = 4096;
constexpr int PDIM   = 512;
constexpr int BDIM   = 4096;
constexpr int PT = 64;    // p per block (one wave-width chunk = 512 floats/row)
constexpr int BT = 32;    // rows per block; 8 per wave, in 4 batches of 2
constexpr float LN2 = 0.69314718055994530942f;

__global__ __launch_bounds__(256, 4)
void box_kernel(const float* __restrict__ x,
                const float* __restrict__ t0,
                const float* __restrict__ t1,
                const float* __restrict__ t2,
                float* __restrict__ out)
{
    __shared__ float tabs[PT][25];           // [p][0..14]=W1, [15..22]=W2 (6.4 KB)
    __shared__ float stage[4][2][2][512];    // [wave][buf][row][elem]     (32 KB)

    const int t    = threadIdx.x;
    const int w    = t >> 6;
    const int lane = t & 63;
    const int p0   = blockIdx.x * PT;
    const int b0   = blockIdx.y * BT;

    // --- per-block gate tables (one p per thread 0..63) ---
    if (t < PT) {
        const int p = p0 + t;
        const float t0p = t0[p], t1p = t1[p], t2p = t2[p];
#pragma unroll
        for (int d = -7; d <= 7; ++d) {
            const float fd = (float)d;
            tabs[t][d + 7] = 1.0f / (1.0f + __expf(-(fd * (t2p - fd))));
        }
#pragma unroll
        for (int m = 0; m < 8; ++m) {
            const float fm = (float)m;
            const float sa = 1.0f / (1.0f + __expf(-((fm - t0p) * (t1p - fm))));
            const float sb = 1.0f / (1.0f + __expf(-((7.0f - t2p - fm) * fm)));
            tabs[t][15 + m] = sa * sb;
        }
    }
    __syncthreads();

    float w1d[15], w2v[8];
#pragma unroll
    for (int i = 0; i < 15; ++i) w1d[i] = tabs[lane][i];
#pragma unroll
    for (int m = 0; m < 8; ++m) w2v[m] = tabs[lane][15 + m];

    // staging: lane s writes float4 f=s (k=0) and f=64+s (k=1) of each row.
    // float4 f holds (g=f>>3, l=f&7, j=0..3); swizzled dword addr
    // W(f) = (f&7)*64 + (((f>>3)^(f&7))<<2)  [k=1 lands at +32]
    const int ls = lane & 7, gh = lane >> 3;
    const int woff = ls * 64 + ((gh ^ ls) << 2);
    float* const wbase = &stage[w][0][0][0];          // [2][2][512] region

    // compute side: lane owns p = p0+lane -> (g=lane>>2, j=lane&3)
    const int gr = lane >> 2, jr = lane & 3;

    const int brow = b0 + w * 8;
    const float* const xrow = x + (size_t)brow * IN_DIM + p0 * 8;
    float* const orow = out + (size_t)brow * PDIM + p0 + lane;

    // prologue: stage batch 0 (rows 0,1) into buf 0
    {
        const float4* s0 = (const float4*)xrow;
        const float4* s1 = (const float4*)(xrow + IN_DIM);
        float4 a0 = s0[lane], a1 = s0[64 + lane];
        float4 a2 = s1[lane], a3 = s1[64 + lane];
        *(float4*)(wbase + woff)            = a0;
        *(float4*)(wbase + woff + 32)       = a1;
        *(float4*)(wbase + 512 + woff)      = a2;
        *(float4*)(wbase + 512 + woff + 32) = a3;
    }

#pragma unroll
    for (int rb = 0; rb < 4; ++rb) {
        // issue next batch's global loads early (hidden under compute)
        float4 n0, n1, n2, n3;
        if (rb < 3) {
            const float4* s0 = (const float4*)(xrow + (size_t)(2 * rb + 2) * IN_DIM);
            const float4* s1 = (const float4*)(xrow + (size_t)(2 * rb + 3) * IN_DIM);
            n0 = s0[lane]; n1 = s0[64 + lane];
            n2 = s1[lane]; n3 = s1[64 + lane];
        }

        const float* buf = wbase + (rb & 1) * 1024;
        float xr[2][8];
#pragma unroll
        for (int l = 0; l < 8; ++l) {
            const int a = l * 64 + ((gr ^ l) << 2) + jr;
            xr[0][l] = buf[a];
            xr[1][l] = buf[512 + a];
        }

        float res[2];
#pragma unroll
        for (int row = 0; row < 2; ++row) {
            float Pn = 1.0f, Pd = 1.0f;
#pragma unroll
            for (int m = 0; m < 8; ++m) {
                float f0 = 1.0f - xr[row][0] * w1d[7 - m];
                float f1 = 1.0f - xr[row][1] * w1d[8 - m];
                float f2 = 1.0f - xr[row][2] * w1d[9 - m];
                float f3 = 1.0f - xr[row][3] * w1d[10 - m];
                float f4 = 1.0f - xr[row][4] * w1d[11 - m];
                float f5 = 1.0f - xr[row][5] * w1d[12 - m];
                float f6 = 1.0f - xr[row][6] * w1d[13 - m];
                float f7 = 1.0f - xr[row][7] * w1d[14 - m];
                const float p1 = ((f0 * f1) * (f2 * f3)) * ((f4 * f5) * (f6 * f7));
                const float den = 1.0f - LN2 * __log2f(p1);   // in [1, 6.55]
                const float num = den - w2v[m];               // >= 0.5
                Pn *= num;
                Pd *= den;
            }
            res[row] = __builtin_amdgcn_rcpf(
                1.0f - LN2 * (__log2f(Pn) - __log2f(Pd)));
        }

        // write next batch into the other buffer (vmcnt wait lands here)
        if (rb < 3) {
            float* wa = wbase + ((rb + 1) & 1) * 1024 + woff;
            *(float4*)(wa)            = n0;
            *(float4*)(wa + 32)       = n1;
            *(float4*)(wa + 512)      = n2;
            *(float4*)(wa + 512 + 32) = n3;
        }

        orow[(size_t)(2 * rb) * PDIM]     = res[0];
        orow[(size_t)(2 * rb + 1) * PDIM] = res[1];
    }
}

extern "C" void kernel_launch(void* const* d_in, const int* in_sizes, int n_in,
                              void* d_out, int out_size, void* d_ws, size_t ws_size,
                              hipStream_t stream)
{
    const float* x  = (const float*)d_in[0];
    const float* t0 = (const float*)d_in[1];
    const float* t1 = (const float*)d_in[2];
    const float* t2 = (const float*)d_in[3];
    float* out = (float*)d_out;

    dim3 grid(PDIM / PT, BDIM / BT);   // (8, 128) = 1024 blocks, 4/CU
    box_kernel<<<grid, 256, 0, stream>>>(x, t0, t1, t2, out);
}